// Round 7
// baseline (52.494 us; speedup 1.0000x reference)
//
#include <hip/hip_runtime.h>
#include <hip/hip_fp16.h>

typedef __attribute__((ext_vector_type(4))) float f32x4;
typedef __attribute__((ext_vector_type(8))) _Float16 f16x8;
typedef __attribute__((ext_vector_type(2))) _Float16 f16x2;
typedef __attribute__((ext_vector_type(2))) __fp16 fp16x2_raw;

union F16X8 { f16x2 p[4]; f16x8 w; };

static __device__ __forceinline__ f16x2 pkrtz(float a, float b) {
    fp16x2_raw r = __builtin_amdgcn_cvt_pkrtz(a, b);  // v_cvt_pkrtz_f16_f32
    return __builtin_bit_cast(f16x2, r);
}

// Load slice dd: B-fragment raw f32 (16 dwords) + 8 diag scales. All indices
// compile-time after unroll -> pure VGPRs, no scratch (rule #20 discipline).
#define LOADB(BUF, dd) do {                                             \
    const float* _p = Sb + (dd) * 4096;                                 \
    _Pragma("unroll") for (int _K = 0; _K < 2; ++_K)                    \
    _Pragma("unroll") for (int _j = 0; _j < 8; ++_j)                    \
        b##BUF[_K][_j] = _p[_K * 2048 + _j * 64];                       \
    const float* _q = qsp + (dd);                                       \
    _Pragma("unroll") for (int _M = 0; _M < 8; ++_M)                    \
        s##BUF[_M] = _q[_M * 1024];                                     \
} while (0)

// Compute slice: convert B to f16, build A = (s_d*q_e) via v_pk_mul_f16, 16 MFMA.
#define COMPUTE(BUF) do {                                               \
    f16x8 _bb[2];                                                       \
    _Pragma("unroll") for (int _K = 0; _K < 2; ++_K) {                  \
        F16X8 _bu;                                                      \
        _Pragma("unroll") for (int _h = 0; _h < 4; ++_h)                \
            _bu.p[_h] = pkrtz(b##BUF[_K][2 * _h], b##BUF[_K][2 * _h + 1]); \
        _bb[_K] = _bu.w;                                                \
    }                                                                   \
    _Pragma("unroll") for (int _M = 0; _M < 8; ++_M) {                  \
        float _sf = 0.125f * s##BUF[_M];                                \
        f16x2 _sh = pkrtz(_sf, _sf);                                    \
        _Pragma("unroll") for (int _K = 0; _K < 2; ++_K) {              \
            F16X8 _au;                                                  \
            _Pragma("unroll") for (int _h = 0; _h < 4; ++_h)            \
                _au.p[_h] = _sh * u[_M][_K][_h];                        \
            acc[_M] = __builtin_amdgcn_mfma_f32_16x16x32_f16(_au.w, _bb[_K], acc[_M], 0, 0, 0); \
        }                                                               \
    }                                                                   \
} while (0)

__global__ __launch_bounds__(256, 1) void quad_form_kernel(
    const float* __restrict__ q, const float* __restrict__ kv, float* __restrict__ out)
{
    const int tid = threadIdx.x;

    // 256 WGs: chunk split into 2 c-halves (WG), wave = 128 rows x 16 f-cols.
    // XCD swizzle: both WGs of a chunk on one XCD (share S slices via L2).
    const int wg = blockIdx.x;             // 0..255
    const int xcd = wg & 7, p = wg >> 3;   // p: 0..31
    const int chunk = xcd * 16 + (p >> 1); // 0..127
    const int chalf = p & 1;

    const int lane = tid & 63;
    const int w = tid >> 6;                // wave id -> f0 = w*16
    const int ra = lane & 15, kg = lane >> 4;
    const int f0 = w * 16;

    const float* qch = q   + (size_t)chunk * 16384 + chalf * 8192;  // 128 rows x 64
    const float* Sch = kv  + (size_t)chunk * 262144;
    float*       och = out + (size_t)chunk * 16384 + chalf * 8192;

    // per-lane bases
    const float* Sb  = Sch + kg * 512 + f0 + ra;  // + d*4096 + Ks*2048 + j*64
    const float* qsp = qch + ra * 64;             // + Mt*1024 + d  (row = Mt*16+ra)

    // ---- hoisted A e-fragments: u[Mt][Ks][h] = packed f16 of q[row][e]*0.125 ----
    f16x2 u[8][2][4];
#pragma unroll
    for (int Mt = 0; Mt < 8; ++Mt)
#pragma unroll
        for (int Ks = 0; Ks < 2; ++Ks) {
            const float* qr = qch + (Mt * 16 + ra) * 64 + Ks * 32 + kg * 8;
            f32x4 g0 = *(const f32x4*)qr;
            f32x4 g1 = *(const f32x4*)(qr + 4);
            u[Mt][Ks][0] = pkrtz(0.125f * g0[0], 0.125f * g0[1]);
            u[Mt][Ks][1] = pkrtz(0.125f * g0[2], 0.125f * g0[3]);
            u[Mt][Ks][2] = pkrtz(0.125f * g1[0], 0.125f * g1[1]);
            u[Mt][Ks][3] = pkrtz(0.125f * g1[2], 0.125f * g1[3]);
        }

    f32x4 acc[8] = {};
    float bA[2][8], bB[2][8];
    float sA[8], sB[8];

    // ---- K-loop over d: distance-2 software pipeline, no barriers, no LDS ----
    LOADB(A, 0);
    LOADB(B, 1);
#pragma unroll 1
    for (int d = 0; d < 62; d += 2) {
        COMPUTE(A);
        LOADB(A, d + 2);
        COMPUTE(B);
        LOADB(B, d + 3);
    }
    COMPUTE(A);
    COMPUTE(B);

    // ---- epilogue: out = 0.5 * acc ----
#pragma unroll
    for (int Mt = 0; Mt < 8; ++Mt)
#pragma unroll
        for (int j = 0; j < 4; ++j)
            och[(Mt * 16 + kg * 4 + j) * 64 + f0 + ra] = 0.5f * acc[Mt][j];
}

extern "C" void kernel_launch(void* const* d_in, const int* in_sizes, int n_in,
                              void* d_out, int out_size, void* d_ws, size_t ws_size,
                              hipStream_t stream) {
    const float* q  = (const float*)d_in[0];
    const float* kv = (const float*)d_in[1];
    float* out = (float*)d_out;
    hipLaunchKernelGGL(quad_form_kernel, dim3(256), dim3(256), 0, stream, q, kv, out);
}

// Round 8
// 38.445 us; speedup vs baseline: 1.3654x; 1.3654x over previous
//
#include <hip/hip_runtime.h>
#include <hip/hip_fp16.h>

typedef __attribute__((ext_vector_type(4))) float f32x4;
typedef __attribute__((ext_vector_type(8))) _Float16 f16x8;
typedef __attribute__((ext_vector_type(2))) _Float16 f16x2;
typedef __attribute__((ext_vector_type(2))) __fp16 fp16x2_raw;

union F16X8 { f16x2 p[4]; f16x8 w; };

static __device__ __forceinline__ f16x2 pkrtz(float a, float b) {
    fp16x2_raw r = __builtin_amdgcn_cvt_pkrtz(a, b);  // v_cvt_pkrtz_f16_f32
    return __builtin_bit_cast(f16x2, r);
}

#define QS 68   // LDS row stride (floats): 272B rows, 16B-aligned; s-reads 2-way (free)

// Load B-fragment for slice dd: 16 coalesced dwords (S is L1-shared across the
// WG's 4 waves). All indices compile-time after unroll -> pure VGPRs.
#define LOADB(BUF, dd) do {                                           \
    const float* _p = Sb + (size_t)(dd) * 4096;                       \
    _Pragma("unroll") for (int _K = 0; _K < 2; ++_K)                  \
    _Pragma("unroll") for (int _j = 0; _j < 8; ++_j)                  \
        b##BUF[_K][_j] = _p[_K * 2048 + _j * 64];                     \
} while (0)

// Compute slice dd: convert B to f16, A = s_d (LDS, pre-scaled) * u_e, 8 MFMA.
#define COMPUTE(BUF, dd) do {                                         \
    f16x8 _bb[2];                                                     \
    _Pragma("unroll") for (int _K = 0; _K < 2; ++_K) {                \
        F16X8 _bu;                                                    \
        _Pragma("unroll") for (int _h = 0; _h < 4; ++_h)              \
            _bu.p[_h] = pkrtz(b##BUF[_K][2*_h], b##BUF[_K][2*_h+1]);  \
        _bb[_K] = _bu.w;                                              \
    }                                                                 \
    _Pragma("unroll") for (int _M = 0; _M < 4; ++_M) {                \
        float _sf = qsbase[_M * (16 * QS) + (dd)];                    \
        f16x2 _sh = pkrtz(_sf, _sf);                                  \
        _Pragma("unroll") for (int _K = 0; _K < 2; ++_K) {            \
            F16X8 _au;                                                \
            _Pragma("unroll") for (int _h = 0; _h < 4; ++_h)          \
                _au.p[_h] = _sh * u[_M][_K][_h];                      \
            acc[_M] = __builtin_amdgcn_mfma_f32_16x16x32_f16(_au.w, _bb[_K], acc[_M], 0, 0, 0); \
        }                                                             \
    }                                                                 \
} while (0)

__global__ __launch_bounds__(256, 2) void quad_form_kernel(
    const float* __restrict__ q, const float* __restrict__ kv, float* __restrict__ out)
{
    __shared__ float qs[256 * QS];   // 69632 B: q chunk * 0.125; 2 WGs/CU fit in 160K

    const int tid = threadIdx.x;

    // f-split: 4 WGs per chunk, each owns 16 f-cols and ALL 256 rows -> S read 1x.
    const int wg = blockIdx.x;             // 0..511
    const int xcd = wg & 7, p = wg >> 3;   // p 0..63
    const int chunk = xcd * 16 + (p >> 2); // 0..127
    const int f0 = (p & 3) * 16;

    const int lane = tid & 63;
    const int w = tid >> 6;                // wave = row-quarter (64 rows)
    const int ra = lane & 15, kg = lane >> 4;

    const float* qch = q  + (size_t)chunk * 16384;
    const float* Sch = kv + (size_t)chunk * 262144;
    float*       och = out + (size_t)chunk * 16384;

    // ---- stage q chunk (256x64) -> LDS, scaled by 0.125 (exact) ----
#pragma unroll
    for (int i = 0; i < 16; ++i) {
        int idx4 = i * 256 + tid;
        int row = idx4 >> 4, col = (idx4 & 15) << 2;
        f32x4 v = *(const f32x4*)(qch + idx4 * 4);
        v *= 0.125f;
        *(f32x4*)&qs[row * QS + col] = v;
    }
    __syncthreads();   // only barrier; qs is read-only afterwards

    // per-lane bases
    const float* Sb = Sch + kg * 512 + f0 + ra;        // + d*4096 + K*2048 + j*64
    const float* qsbase = &qs[(w * 64 + ra) * QS];     // + Mt*16*QS + d  (s broadcast)

    // ---- hoisted A e-fragments u[Mt][Ks][h] (f16, pre-scaled by 1/8) ----
    f16x2 u[4][2][4];
#pragma unroll
    for (int Mt = 0; Mt < 4; ++Mt)
#pragma unroll
        for (int Ks = 0; Ks < 2; ++Ks) {
            const float* qr = qsbase + Mt * (16 * QS) + Ks * 32 + kg * 8;
            f32x4 g0 = *(const f32x4*)qr;
            f32x4 g1 = *(const f32x4*)(qr + 4);
            u[Mt][Ks][0] = pkrtz(g0[0], g0[1]);
            u[Mt][Ks][1] = pkrtz(g0[2], g0[3]);
            u[Mt][Ks][2] = pkrtz(g1[0], g1[1]);
            u[Mt][Ks][3] = pkrtz(g1[2], g1[3]);
        }

    f32x4 acc[4] = {};
    float bA[2][8], bB[2][8], bC[2][8];   // 3-deep rotation: 2-slice consume window

    LOADB(A, 0); LOADB(B, 1); LOADB(C, 2);

    int i = 0;
#pragma unroll 1
    for (int it = 0; it < 21; ++it) {      // slices 0..62
        COMPUTE(A, i); if (i + 3 < 64) LOADB(A, i + 3); ++i;
        COMPUTE(B, i); if (i + 3 < 64) LOADB(B, i + 3); ++i;
        COMPUTE(C, i); if (i + 3 < 64) LOADB(C, i + 3); ++i;
    }
    COMPUTE(A, 63);                        // 63 % 3 == 0 -> buffer A

    // ---- epilogue: out = 0.5 * acc ----
#pragma unroll
    for (int Mt = 0; Mt < 4; ++Mt)
#pragma unroll
        for (int j = 0; j < 4; ++j)
            och[(w * 64 + Mt * 16 + kg * 4 + j) * 64 + f0 + ra] = 0.5f * acc[Mt][j];
}

extern "C" void kernel_launch(void* const* d_in, const int* in_sizes, int n_in,
                              void* d_out, int out_size, void* d_ws, size_t ws_size,
                              hipStream_t stream) {
    const float* q  = (const float*)d_in[0];
    const float* kv = (const float*)d_in[1];
    float* out = (float*)d_out;
    hipLaunchKernelGGL(quad_form_kernel, dim3(512), dim3(256), 0, stream, q, kv, out);
}